// Round 1
// baseline (1080.893 us; speedup 1.0000x reference)
//
#include <hip/hip_runtime.h>
#include <cstdint>
#include <cstddef>

// ---------------------------------------------------------------------------
// WeightedTemporalSelfAttention on MI355X.
//   out = softmax((xWq (xWk)^T + chan_bias)/sqrt(2048)) @ (xWv) + b_ch + b_t[0] + PE(0)
// Precision: softmax is near-one-hot, so q,k and QK^T use split-fp16
// (hi+lo -> 3 accumulation passes, ~2^-22 input precision).
// v and attn@v use plain fp16 (linear, tolerant).
// This round: q/k and S GEMMs moved to a 256x256 4-phase/K-tile pipelined
// kernel (counted vmcnt, LDS XOR swizzle, setprio) -- T2+T3+T4+T5 stack.
// ---------------------------------------------------------------------------

using h8    = __attribute__((ext_vector_type(8))) _Float16;
using h4    = __attribute__((ext_vector_type(4))) _Float16;
using f32x4 = __attribute__((ext_vector_type(4))) float;

__device__ __forceinline__ void gll16(const void* g, void* l) {
  // async global->LDS, 16B/lane; LDS dest = wave-uniform base + lane*16
  __builtin_amdgcn_global_load_lds(
      (const __attribute__((address_space(1))) uint32_t*)g,
      (__attribute__((address_space(3))) uint32_t*)l, 16, 0, 0);
}

// ---------------- elementwise split: fp32 -> fp16 hi + fp16 lo --------------
__global__ __launch_bounds__(256) void split_x_kernel(
    const float* __restrict__ X, _Float16* __restrict__ hi,
    _Float16* __restrict__ lo, int n4)
{
  int i = blockIdx.x * 256 + threadIdx.x;
  if (i >= n4) return;
  float4 v = ((const float4*)X)[i];
  float a[4] = {v.x, v.y, v.z, v.w};
  h4 hh, ll;
#pragma unroll
  for (int e = 0; e < 4; ++e) {
    _Float16 h = (_Float16)a[e];
    hh[e] = h;
    ll[e] = (_Float16)(a[e] - (float)h);
  }
  ((h4*)hi)[i] = hh;
  ((h4*)lo)[i] = ll;
}

// ------------- transpose + split: W[k][n] fp32 -> T{hi,lo}[n][k] fp16 -------
__global__ __launch_bounds__(256) void transpose_split_w(
    const float* __restrict__ W, _Float16* __restrict__ Thi,
    _Float16* __restrict__ Tlo, int D, int writeLo)
{
  __shared__ float t[32][33];
  int n0 = blockIdx.x * 32;
  int k0 = blockIdx.y * 32;
  int tx = threadIdx.x & 31;
  int ty = threadIdx.x >> 5;  // 0..7
  for (int j = ty; j < 32; j += 8)
    t[j][tx] = W[(size_t)(k0 + j) * D + n0 + tx];
  __syncthreads();
  for (int j = ty; j < 32; j += 8) {
    float v = t[tx][j];                          // W[k0+tx][n0+j]
    size_t o = (size_t)(n0 + j) * D + k0 + tx;   // T[n][k]
    _Float16 h = (_Float16)v;
    Thi[o] = h;
    if (writeLo) Tlo[o] = (_Float16)(v - (float)h);
  }
}

// ---------------------------- tiled MFMA GEMM (128x128, legacy) ------------
// C[M,N] = A[M,K] * Bt[N,K]^T   (both operands row-major with K contiguous)
// kept for the v GEMM (EPI_VT) and the ctx GEMM (EPI_CTX), whose N=2048
// grids fill the GPU at this tile size.
constexpr int EPI_QK = 0;   // write C as fp16 hi/lo pair (row-major, ldc)
constexpr int EPI_VT = 1;   // write C^T as fp16 (oh1[col*ldt + row])
constexpr int EPI_S  = 2;   // write C fp32 (row-major, ldc)
constexpr int EPI_CTX = 3;  // out = C + c1 + c2 + PE(odd cols +1), fp32

template<int EPI, bool SPLIT>
__global__ __launch_bounds__(256, 2) void gemm_bt(
    const _Float16* __restrict__ A, const _Float16* __restrict__ Al,
    const _Float16* __restrict__ B, const _Float16* __restrict__ Bl,
    int K, int lda, int ldb, int ldc, int ldt,
    float* __restrict__ of32, _Float16* __restrict__ oh1,
    _Float16* __restrict__ oh2,
    const float* __restrict__ c1, const float* __restrict__ c2)
{
  __shared__ __align__(16) _Float16 sA [128 * 32];
  __shared__ __align__(16) _Float16 sB [128 * 32];
  __shared__ __align__(16) _Float16 sAl[SPLIT ? 128 * 32 : 8];
  __shared__ __align__(16) _Float16 sBl[SPLIT ? 128 * 32 : 8];

  const int tid  = threadIdx.x;
  const int lane = tid & 63;
  const int wave = tid >> 6;
  const int wm = wave >> 1, wn = wave & 1;
  const int m0 = blockIdx.y * 128, n0 = blockIdx.x * 128;

  const int ca = lane + 64 * wave;
  const int ra = ca >> 2, ka = (ca & 3) * 8;
  const int cc = ca + 256;
  const int rb = cc >> 2, kb = (cc & 3) * 8;
  const size_t lo0 = (size_t)wave * 1024;
  const size_t lo1 = lo0 + 4096;

  const _Float16* gA0 = A + (size_t)(m0 + ra) * lda + ka;
  const _Float16* gA1 = A + (size_t)(m0 + rb) * lda + kb;
  const _Float16* gB0 = B + (size_t)(n0 + ra) * ldb + ka;
  const _Float16* gB1 = B + (size_t)(n0 + rb) * ldb + kb;
  const _Float16* gAl0 = Al ? Al + (size_t)(m0 + ra) * lda + ka : nullptr;
  const _Float16* gAl1 = Al ? Al + (size_t)(m0 + rb) * lda + kb : nullptr;
  const _Float16* gBl0 = Bl ? Bl + (size_t)(n0 + ra) * ldb + ka : nullptr;
  const _Float16* gBl1 = Bl ? Bl + (size_t)(n0 + rb) * ldb + kb : nullptr;

  f32x4 acc[4][4];
#pragma unroll
  for (int i = 0; i < 4; ++i)
#pragma unroll
    for (int j = 0; j < 4; ++j) acc[i][j] = (f32x4){0.f, 0.f, 0.f, 0.f};

  const int fr = lane & 15;
  const int fk = (lane >> 4) * 8;

  for (int k0 = 0; k0 < K; k0 += 32) {
    gll16(gA0 + k0, (char*)sA + lo0);
    gll16(gA1 + k0, (char*)sA + lo1);
    gll16(gB0 + k0, (char*)sB + lo0);
    gll16(gB1 + k0, (char*)sB + lo1);
    if constexpr (SPLIT) {
      gll16(gAl0 + k0, (char*)sAl + lo0);
      gll16(gAl1 + k0, (char*)sAl + lo1);
      gll16(gBl0 + k0, (char*)sBl + lo0);
      gll16(gBl1 + k0, (char*)sBl + lo1);
    }
    __syncthreads();

    h8 af[4], bf[4], afl[4], bfl[4];
#pragma unroll
    for (int mi = 0; mi < 4; ++mi)
      af[mi] = *(const h8*)&sA[(wm * 64 + mi * 16 + fr) * 32 + fk];
#pragma unroll
    for (int ni = 0; ni < 4; ++ni)
      bf[ni] = *(const h8*)&sB[(wn * 64 + ni * 16 + fr) * 32 + fk];
    if constexpr (SPLIT) {
#pragma unroll
      for (int mi = 0; mi < 4; ++mi)
        afl[mi] = *(const h8*)&sAl[(wm * 64 + mi * 16 + fr) * 32 + fk];
#pragma unroll
      for (int ni = 0; ni < 4; ++ni)
        bfl[ni] = *(const h8*)&sBl[(wn * 64 + ni * 16 + fr) * 32 + fk];
    }

#pragma unroll
    for (int mi = 0; mi < 4; ++mi)
#pragma unroll
      for (int ni = 0; ni < 4; ++ni) {
        acc[mi][ni] = __builtin_amdgcn_mfma_f32_16x16x32_f16(
            af[mi], bf[ni], acc[mi][ni], 0, 0, 0);
        if constexpr (SPLIT) {
          acc[mi][ni] = __builtin_amdgcn_mfma_f32_16x16x32_f16(
              af[mi], bfl[ni], acc[mi][ni], 0, 0, 0);
          acc[mi][ni] = __builtin_amdgcn_mfma_f32_16x16x32_f16(
              afl[mi], bf[ni], acc[mi][ni], 0, 0, 0);
        }
      }
    __syncthreads();
  }

  const int drow = (lane >> 4) * 4;
  const int dcol = lane & 15;
#pragma unroll
  for (int mi = 0; mi < 4; ++mi) {
#pragma unroll
    for (int ni = 0; ni < 4; ++ni) {
      const int row = m0 + wm * 64 + mi * 16 + drow;
      const int col = n0 + wn * 64 + ni * 16 + dcol;
      f32x4 v = acc[mi][ni];
      if constexpr (EPI == EPI_S) {
#pragma unroll
        for (int r = 0; r < 4; ++r)
          of32[(size_t)(row + r) * ldc + col] = v[r];
      } else if constexpr (EPI == EPI_QK) {
#pragma unroll
        for (int r = 0; r < 4; ++r) {
          float x = v[r];
          _Float16 hh = (_Float16)x;
          size_t o = (size_t)(row + r) * ldc + col;
          oh1[o] = hh;
          oh2[o] = (_Float16)(x - (float)hh);
        }
      } else if constexpr (EPI == EPI_VT) {
        h4 hh;
#pragma unroll
        for (int r = 0; r < 4; ++r) hh[r] = (_Float16)v[r];
        *(h4*)&oh1[(size_t)col * ldt + row] = hh;
      } else {  // EPI_CTX
#pragma unroll
        for (int r = 0; r < 4; ++r) {
          size_t o = (size_t)(row + r) * ldc + col;
          of32[o] = v[r] + c1[o] + c2[o] + ((col & 1) ? 1.0f : 0.0f);
        }
      }
    }
  }
}

// ---------------------------------------------------------------------------
// 256x256 pipelined GEMM: C[M,N] = sum_p A_p[M,2048] * B_p[N,2048]^T
// 512 thr = 8 waves (2m x 4n); per-wave 128x64 out; K-tile BK=64 as 2 kk-halves.
// LDS 144KB: A[2buf][2kk][256 rows][4 slots*16B] @0 | B same @65536 | dummy @131072.
// Swizzle: phys_slot = logical_slot ^ ((row>>1)&3). global_load_lds writes
// linearly, so the inverse swizzle is applied to the per-lane GLOBAL source
// (rule: both-sides-or-neither). ds_read_b128 conflicts <= 2-way (free).
//
// Schedule per tile t (buf=t&1), 4 phases, one 16KB half-block staged/phase:
//   ph0: read A(buf,k0,mi0-3)+B(buf,k0) | stage (t+1).A_k1 -> buf^1 | mfma
//   ph1: read A(buf,k0,mi4-7)           | stage (t+1).B_k1 -> buf^1 | mfma | vmcnt(8)
//   ph2: read A(buf,k1,mi0-3)+B(buf,k1) | stage (t+2).A_k0 -> buf   | mfma
//   ph3: read A(buf,k1,mi4-7)           | stage (t+2).B_k0 -> buf   | mfma | vmcnt(8)
// Race-free: (t+2) writes only kk0 of the live buffer, whose ds_reads all
// completed before ph1's closing barrier. vmcnt(8) = 4 younger half-blocks
// (2 loads each) allowed in flight; the wait sits BEFORE the closing barrier
// so after the barrier every wave's needed data is resident. Past-the-end
// stages go to a dummy LDS region to keep the vmcnt accounting uniform.
// ---------------------------------------------------------------------------
template<int EPI, int NPASS>
__global__ __launch_bounds__(512, 2) void gemm256(
    const _Float16* __restrict__ A0, const _Float16* __restrict__ B0,
    const _Float16* __restrict__ A1, const _Float16* __restrict__ B1,
    const _Float16* __restrict__ A2, const _Float16* __restrict__ B2,
    int lda, int ldb, int ldc,
    float* __restrict__ of32, _Float16* __restrict__ oh1,
    _Float16* __restrict__ oh2)
{
  __shared__ __align__(16) char lds[147456];
  constexpr int T = NPASS * 32;     // 32 K-tiles of 64 per 2048-deep pass

  const int tid  = threadIdx.x;
  const int lane = tid & 63;
  const int w    = tid >> 6;
  const int wm = w >> 2, wn = w & 3;
  const int fr = lane & 15, sl = lane >> 4;
  const int m0 = blockIdx.y * 256, n0 = blockIdx.x * 256;

  const int sswz  = ((sl ^ ((fr >> 1) & 3)) << 4);      // swizzled 16B slot
  const int aBase = (wm * 128 + fr) * 64 + sswz;        // byte offs in A block
  const int bBase = 65536 + (wn * 64 + fr) * 64 + sswz; // byte offs in B block
  const int rowoff = w * 16 + (lane >> 2);              // staging row
  const int sL8 = ((lane & 3) ^ ((lane >> 3) & 3)) * 8; // inv-swz global slot

  auto gstage = [&](int t, int isB, int kk) {
    const _Float16* g; int ld, r0, gk; char* dst;
    if (t >= T) {                      // dummy stage: keeps vmcnt uniform
      g = A0; ld = lda; r0 = m0; gk = 0; dst = lds + 131072;
    } else {
      const int p = t >> 5, kt = t & 31;
      g  = isB ? (p == 0 ? B0 : (p == 1 ? B1 : B2))
               : (p == 0 ? A0 : (p == 1 ? A1 : A2));
      ld = isB ? ldb : lda;
      r0 = isB ? n0 : m0;
      gk = kt * 64 + kk * 32;
      dst = lds + (isB ? 65536 : 0) + (t & 1) * 32768 + kk * 16384;
    }
#pragma unroll
    for (int i = 0; i < 2; ++i)
      gll16(g + (size_t)(r0 + i * 128 + rowoff) * ld + gk + sL8,
            dst + i * 8192 + w * 1024);
  };

  f32x4 acc[8][4];
#pragma unroll
  for (int i = 0; i < 8; ++i)
#pragma unroll
    for (int j = 0; j < 4; ++j) acc[i][j] = (f32x4){0.f, 0.f, 0.f, 0.f};

  // prologue: tile0 fully + tile1 kk0 (6 half-blocks = 12 loads/thread);
  // vmcnt(8) -> the 4 oldest (t0.A_k0, t0.B_k0) are resident.
  gstage(0, 0, 0); gstage(0, 1, 0);
  gstage(0, 0, 1); gstage(0, 1, 1);
  gstage(1, 0, 0); gstage(1, 1, 0);
  asm volatile("s_waitcnt vmcnt(8)" ::: "memory");
  __builtin_amdgcn_sched_barrier(0);
  __builtin_amdgcn_s_barrier();

  h8 af[4], bf[4];
#pragma unroll 2
  for (int t = 0; t < T; ++t) {
    const char* aB = lds + (t & 1) * 32768;

    // ---- ph0: kk=0, mi 0..3 ----
#pragma unroll
    for (int i = 0; i < 4; ++i) af[i] = *(const h8*)(aB + aBase + i * 1024);
#pragma unroll
    for (int i = 0; i < 4; ++i) bf[i] = *(const h8*)(aB + bBase + i * 1024);
    gstage(t + 1, 0, 1);
    __builtin_amdgcn_s_barrier();
    asm volatile("s_waitcnt lgkmcnt(0)" ::: "memory");
    __builtin_amdgcn_sched_barrier(0);
    __builtin_amdgcn_s_setprio(1);
#pragma unroll
    for (int mi = 0; mi < 4; ++mi)
#pragma unroll
      for (int ni = 0; ni < 4; ++ni)
        acc[mi][ni] = __builtin_amdgcn_mfma_f32_16x16x32_f16(
            af[mi], bf[ni], acc[mi][ni], 0, 0, 0);
    __builtin_amdgcn_s_setprio(0);
    __builtin_amdgcn_s_barrier();

    // ---- ph1: kk=0, mi 4..7 (bf reused) ----
#pragma unroll
    for (int i = 0; i < 4; ++i)
      af[i] = *(const h8*)(aB + aBase + (4 + i) * 1024);
    gstage(t + 1, 1, 1);
    __builtin_amdgcn_s_barrier();
    asm volatile("s_waitcnt lgkmcnt(0)" ::: "memory");
    __builtin_amdgcn_sched_barrier(0);
    __builtin_amdgcn_s_setprio(1);
#pragma unroll
    for (int mi = 0; mi < 4; ++mi)
#pragma unroll
      for (int ni = 0; ni < 4; ++ni)
        acc[4 + mi][ni] = __builtin_amdgcn_mfma_f32_16x16x32_f16(
            af[mi], bf[ni], acc[4 + mi][ni], 0, 0, 0);
    __builtin_amdgcn_s_setprio(0);
    asm volatile("s_waitcnt vmcnt(8)" ::: "memory");   // t.kk1 now resident
    __builtin_amdgcn_sched_barrier(0);
    __builtin_amdgcn_s_barrier();

    // ---- ph2: kk=1, mi 0..3 ----
#pragma unroll
    for (int i = 0; i < 4; ++i)
      af[i] = *(const h8*)(aB + 16384 + aBase + i * 1024);
#pragma unroll
    for (int i = 0; i < 4; ++i)
      bf[i] = *(const h8*)(aB + 16384 + bBase + i * 1024);
    gstage(t + 2, 0, 0);
    __builtin_amdgcn_s_barrier();
    asm volatile("s_waitcnt lgkmcnt(0)" ::: "memory");
    __builtin_amdgcn_sched_barrier(0);
    __builtin_amdgcn_s_setprio(1);
#pragma unroll
    for (int mi = 0; mi < 4; ++mi)
#pragma unroll
      for (int ni = 0; ni < 4; ++ni)
        acc[mi][ni] = __builtin_amdgcn_mfma_f32_16x16x32_f16(
            af[mi], bf[ni], acc[mi][ni], 0, 0, 0);
    __builtin_amdgcn_s_setprio(0);
    __builtin_amdgcn_s_barrier();

    // ---- ph3: kk=1, mi 4..7 (bf reused) ----
#pragma unroll
    for (int i = 0; i < 4; ++i)
      af[i] = *(const h8*)(aB + 16384 + aBase + (4 + i) * 1024);
    gstage(t + 2, 1, 0);
    __builtin_amdgcn_s_barrier();
    asm volatile("s_waitcnt lgkmcnt(0)" ::: "memory");
    __builtin_amdgcn_sched_barrier(0);
    __builtin_amdgcn_s_setprio(1);
#pragma unroll
    for (int mi = 0; mi < 4; ++mi)
#pragma unroll
      for (int ni = 0; ni < 4; ++ni)
        acc[4 + mi][ni] = __builtin_amdgcn_mfma_f32_16x16x32_f16(
            af[mi], bf[ni], acc[4 + mi][ni], 0, 0, 0);
    __builtin_amdgcn_s_setprio(0);
    asm volatile("s_waitcnt vmcnt(8)" ::: "memory");   // (t+1).kk0 resident
    __builtin_amdgcn_sched_barrier(0);
    __builtin_amdgcn_s_barrier();
  }
  asm volatile("s_waitcnt vmcnt(0)" ::: "memory");     // drain dummy stages

  // C/D frag: col = lane&15, row = (lane>>4)*4 + reg
  const int drow = sl * 4;
#pragma unroll
  for (int mi = 0; mi < 8; ++mi) {
#pragma unroll
    for (int ni = 0; ni < 4; ++ni) {
      const int row = m0 + wm * 128 + mi * 16 + drow;
      const int col = n0 + wn * 64 + ni * 16 + fr;
      f32x4 v = acc[mi][ni];
      if constexpr (EPI == EPI_S) {
#pragma unroll
        for (int r = 0; r < 4; ++r)
          of32[(size_t)(row + r) * ldc + col] = v[r];
      } else {  // EPI_QK
#pragma unroll
        for (int r = 0; r < 4; ++r) {
          float x = v[r];
          _Float16 hh = (_Float16)x;
          size_t o = (size_t)(row + r) * ldc + col;
          oh1[o] = hh;
          oh2[o] = (_Float16)(x - (float)hh);
        }
      }
    }
  }
}

// ------------- row softmax with channel bias; in-place fp32 -> fp16 --------
__global__ __launch_bounds__(256) void softmax_bias_kernel(
    float* __restrict__ S, int N)
{
  const float scale = 0.022097086912079608f;  // 1/sqrt(2048)
  const int row = blockIdx.x;
  float* rp = S + (size_t)row * N;
  const int cblk = row & ~63;  // channel block start (CW=64)
  const int tid = threadIdx.x;

  float vals[16];
  float mx = -3.0e38f;
#pragma unroll
  for (int it = 0; it < 4; ++it) {
    int base = (it * 256 + tid) * 4;
    float4 v = *(const float4*)(rp + base);
    float a[4] = {v.x, v.y, v.z, v.w};
#pragma unroll
    for (int e = 0; e < 4; ++e) {
      int col = base + e;
      float s = a[e];
      if ((col & ~63) == cblk) s += 1.0f;  // bias BEFORE scaling (reference)
      s *= scale;
      vals[it * 4 + e] = s;
      mx = fmaxf(mx, s);
    }
  }
  __shared__ float red[8];
#pragma unroll
  for (int m = 32; m; m >>= 1) mx = fmaxf(mx, __shfl_xor(mx, m, 64));
  if ((tid & 63) == 0) red[tid >> 6] = mx;
  __syncthreads();
  mx = fmaxf(fmaxf(red[0], red[1]), fmaxf(red[2], red[3]));

  float sum = 0.f;
#pragma unroll
  for (int i = 0; i < 16; ++i) {
    float e = __expf(vals[i] - mx);
    vals[i] = e;
    sum += e;
  }
#pragma unroll
  for (int m = 32; m; m >>= 1) sum += __shfl_xor(sum, m, 64);
  if ((tid & 63) == 0) red[4 + (tid >> 6)] = sum;
  __syncthreads();
  sum = red[4] + red[5] + red[6] + red[7];
  float inv = 1.0f / sum;

  _Float16* op = (_Float16*)rp;  // in-place: fp16 attn over first half of row
#pragma unroll
  for (int it = 0; it < 4; ++it) {
    int base = (it * 256 + tid) * 4;
    h4 hh;
#pragma unroll
    for (int e = 0; e < 4; ++e) hh[e] = (_Float16)(vals[it * 4 + e] * inv);
    *(h4*)(op + base) = hh;
  }
}

// ---------------------------------------------------------------------------
extern "C" void kernel_launch(void* const* d_in, const int* in_sizes, int n_in,
                              void* d_out, int out_size, void* d_ws,
                              size_t ws_size, hipStream_t stream)
{
  (void)in_sizes; (void)n_in; (void)out_size; (void)ws_size;
  const float* x   = (const float*)d_in[0];  // [4096,2048]
  const float* Wq  = (const float*)d_in[1];  // [2048,2048]
  const float* Wk  = (const float*)d_in[2];
  const float* Wv  = (const float*)d_in[3];
  const float* bch = (const float*)d_in[4];  // [4096,2048]
  const float* bt0 = (const float*)d_in[5];  // b_t[0] = first slice
  float* out = (float*)d_out;

  char* ws = (char*)d_ws;
  // phase-1 region [0, 64MiB): x split + merged W_qk split; S (64MiB fp32)
  // aliases it after the qk and v GEMMs are done with those inputs.
  const size_t O_XHI  = 0;                    // 16 MiB
  const size_t O_XLO  = O_XHI + 16777216;     // 16 MiB
  const size_t O_WQKH = O_XLO + 16777216;     // [Wq;Wk] hi, [4096][2048] fp16
  const size_t O_WQKL = O_WQKH + 16777216;    // [Wq;Wk] lo       -> 64 MiB
  const size_t O_S    = 0;                    // fp32 scores, 64 MiB (alias)
  const size_t O_WVH  = 67108864;             // 8 MiB
  const size_t O_VT   = O_WVH + 8388608;      // 16 MiB (v^T fp16)
  const size_t O_QKH  = O_VT + 16777216;      // [q|k] hi, [4096][4096] fp16
  const size_t O_QKL  = O_QKH + 33554432;     // [q|k] lo -> total 159383552 B

  _Float16* xhi  = (_Float16*)(ws + O_XHI);
  _Float16* xlo  = (_Float16*)(ws + O_XLO);
  _Float16* wqkh = (_Float16*)(ws + O_WQKH);
  _Float16* wqkl = (_Float16*)(ws + O_WQKL);
  _Float16* wvh  = (_Float16*)(ws + O_WVH);
  _Float16* vT   = (_Float16*)(ws + O_VT);
  _Float16* qkh  = (_Float16*)(ws + O_QKH);
  _Float16* qkl  = (_Float16*)(ws + O_QKL);
  float*    S    = (float*)(ws + O_S);

  // 1) split x (8.4M elems, float4-vectorized)
  split_x_kernel<<<2097152 / 256, 256, 0, stream>>>(x, xhi, xlo, 2097152);
  // 2) transpose+split weights; Wq rows 0..2047, Wk rows 2048..4095 (merged)
  dim3 tg(64, 64);
  transpose_split_w<<<tg, 256, 0, stream>>>(Wq, wqkh, wqkl, 2048, 1);
  transpose_split_w<<<tg, 256, 0, stream>>>(
      Wk, wqkh + (size_t)2048 * 2048, wqkl + (size_t)2048 * 2048, 2048, 1);
  transpose_split_w<<<tg, 256, 0, stream>>>(Wv, wvh, nullptr, 2048, 0);

  // 3) [q|k] = x @ [Wq|Wk]  -- split as 3 passes: Ahi*Bhi + Ahi*Blo + Alo*Bhi
  //    N=4096 -> grid 16x16 = 256 blocks = 1 per CU.
  gemm256<EPI_QK, 3><<<dim3(16, 16), 512, 0, stream>>>(
      xhi, wqkh, xhi, wqkl, xlo, wqkh, 2048, 2048, 4096,
      nullptr, qkh, qkl);
  // 4) vT = (x@Wv)^T  (plain fp16, 128^2 kernel: N=2048 grid fills GPU there)
  gemm_bt<EPI_VT, false><<<dim3(16, 32), 256, 0, stream>>>(
      xhi, nullptr, wvh, nullptr, 2048, 2048, 2048, 0, 4096,
      nullptr, vT, nullptr, nullptr, nullptr);

  // 5) S = q@k^T -- split 3 passes; q = qk cols 0..2047, k = qk cols 2048..4095
  gemm256<EPI_S, 3><<<dim3(16, 16), 512, 0, stream>>>(
      qkh, qkh + 2048, qkh, qkl + 2048, qkl, qkh + 2048, 4096, 4096, 4096,
      S, nullptr, nullptr);

  // 6) softmax((S + chan_bias)/sqrt(d)) -> attn fp16, in place
  softmax_bias_kernel<<<4096, 256, 0, stream>>>(S, 4096);

  // 7) out = attn@v + b_channel + b_t[0] + PE(0)  (attn lda = 8192 halves)
  gemm_bt<EPI_CTX, false><<<dim3(16, 32), 256, 0, stream>>>(
      (const _Float16*)S, nullptr, vT, nullptr, 4096, 8192, 4096, 2048, 0,
      out, nullptr, nullptr, bch, bt0);
}

// Round 2
// 932.481 us; speedup vs baseline: 1.1592x; 1.1592x over previous
//
#include <hip/hip_runtime.h>
#include <cstdint>
#include <cstddef>

// ---------------------------------------------------------------------------
// WeightedTemporalSelfAttention on MI355X.
//   out = softmax((xWq (xWk)^T + chan_bias)/sqrt(2048)) @ (xWv) + b_ch + b_t[0] + PE(0)
// Precision: softmax is near-one-hot, so q,k and QK^T use split-fp16
// (hi+lo -> 3 accumulation passes, ~2^-22 input precision).
// v and attn@v use plain fp16 (linear, tolerant).
// Round 2: gemm256 flattened from 4 phases/8 barriers per K-tile to
// 2 super-phases/2 barriers; removed hand lgkmcnt(0)+sched_barrier pins so
// the compiler software-pipelines ds_read -> MFMA with fine-grained waits.
// ---------------------------------------------------------------------------

using h8    = __attribute__((ext_vector_type(8))) _Float16;
using h4    = __attribute__((ext_vector_type(4))) _Float16;
using f32x4 = __attribute__((ext_vector_type(4))) float;

__device__ __forceinline__ void gll16(const void* g, void* l) {
  // async global->LDS, 16B/lane; LDS dest = wave-uniform base + lane*16
  __builtin_amdgcn_global_load_lds(
      (const __attribute__((address_space(1))) uint32_t*)g,
      (__attribute__((address_space(3))) uint32_t*)l, 16, 0, 0);
}

// ---------------- elementwise split: fp32 -> fp16 hi + fp16 lo --------------
__global__ __launch_bounds__(256) void split_x_kernel(
    const float* __restrict__ X, _Float16* __restrict__ hi,
    _Float16* __restrict__ lo, int n4)
{
  int i = blockIdx.x * 256 + threadIdx.x;
  if (i >= n4) return;
  float4 v = ((const float4*)X)[i];
  float a[4] = {v.x, v.y, v.z, v.w};
  h4 hh, ll;
#pragma unroll
  for (int e = 0; e < 4; ++e) {
    _Float16 h = (_Float16)a[e];
    hh[e] = h;
    ll[e] = (_Float16)(a[e] - (float)h);
  }
  ((h4*)hi)[i] = hh;
  ((h4*)lo)[i] = ll;
}

// ------------- transpose + split: W[k][n] fp32 -> T{hi,lo}[n][k] fp16 -------
__global__ __launch_bounds__(256) void transpose_split_w(
    const float* __restrict__ W, _Float16* __restrict__ Thi,
    _Float16* __restrict__ Tlo, int D, int writeLo)
{
  __shared__ float t[32][33];
  int n0 = blockIdx.x * 32;
  int k0 = blockIdx.y * 32;
  int tx = threadIdx.x & 31;
  int ty = threadIdx.x >> 5;  // 0..7
  for (int j = ty; j < 32; j += 8)
    t[j][tx] = W[(size_t)(k0 + j) * D + n0 + tx];
  __syncthreads();
  for (int j = ty; j < 32; j += 8) {
    float v = t[tx][j];                          // W[k0+tx][n0+j]
    size_t o = (size_t)(n0 + j) * D + k0 + tx;   // T[n][k]
    _Float16 h = (_Float16)v;
    Thi[o] = h;
    if (writeLo) Tlo[o] = (_Float16)(v - (float)h);
  }
}

// ---------------------------- tiled MFMA GEMM (128x128, legacy) ------------
// C[M,N] = A[M,K] * Bt[N,K]^T   (both operands row-major with K contiguous)
// kept for the v GEMM (EPI_VT) and the ctx GEMM (EPI_CTX), whose N=2048
// grids fill the GPU at this tile size.
constexpr int EPI_QK = 0;   // write C as fp16 hi/lo pair (row-major, ldc)
constexpr int EPI_VT = 1;   // write C^T as fp16 (oh1[col*ldt + row])
constexpr int EPI_S  = 2;   // write C fp32 (row-major, ldc)
constexpr int EPI_CTX = 3;  // out = C + c1 + c2 + PE(odd cols +1), fp32

template<int EPI, bool SPLIT>
__global__ __launch_bounds__(256, 2) void gemm_bt(
    const _Float16* __restrict__ A, const _Float16* __restrict__ Al,
    const _Float16* __restrict__ B, const _Float16* __restrict__ Bl,
    int K, int lda, int ldb, int ldc, int ldt,
    float* __restrict__ of32, _Float16* __restrict__ oh1,
    _Float16* __restrict__ oh2,
    const float* __restrict__ c1, const float* __restrict__ c2)
{
  __shared__ __align__(16) _Float16 sA [128 * 32];
  __shared__ __align__(16) _Float16 sB [128 * 32];
  __shared__ __align__(16) _Float16 sAl[SPLIT ? 128 * 32 : 8];
  __shared__ __align__(16) _Float16 sBl[SPLIT ? 128 * 32 : 8];

  const int tid  = threadIdx.x;
  const int lane = tid & 63;
  const int wave = tid >> 6;
  const int wm = wave >> 1, wn = wave & 1;
  const int m0 = blockIdx.y * 128, n0 = blockIdx.x * 128;

  const int ca = lane + 64 * wave;
  const int ra = ca >> 2, ka = (ca & 3) * 8;
  const int cc = ca + 256;
  const int rb = cc >> 2, kb = (cc & 3) * 8;
  const size_t lo0 = (size_t)wave * 1024;
  const size_t lo1 = lo0 + 4096;

  const _Float16* gA0 = A + (size_t)(m0 + ra) * lda + ka;
  const _Float16* gA1 = A + (size_t)(m0 + rb) * lda + kb;
  const _Float16* gB0 = B + (size_t)(n0 + ra) * ldb + ka;
  const _Float16* gB1 = B + (size_t)(n0 + rb) * ldb + kb;
  const _Float16* gAl0 = Al ? Al + (size_t)(m0 + ra) * lda + ka : nullptr;
  const _Float16* gAl1 = Al ? Al + (size_t)(m0 + rb) * lda + kb : nullptr;
  const _Float16* gBl0 = Bl ? Bl + (size_t)(n0 + ra) * ldb + ka : nullptr;
  const _Float16* gBl1 = Bl ? Bl + (size_t)(n0 + rb) * ldb + kb : nullptr;

  f32x4 acc[4][4];
#pragma unroll
  for (int i = 0; i < 4; ++i)
#pragma unroll
    for (int j = 0; j < 4; ++j) acc[i][j] = (f32x4){0.f, 0.f, 0.f, 0.f};

  const int fr = lane & 15;
  const int fk = (lane >> 4) * 8;

  for (int k0 = 0; k0 < K; k0 += 32) {
    gll16(gA0 + k0, (char*)sA + lo0);
    gll16(gA1 + k0, (char*)sA + lo1);
    gll16(gB0 + k0, (char*)sB + lo0);
    gll16(gB1 + k0, (char*)sB + lo1);
    if constexpr (SPLIT) {
      gll16(gAl0 + k0, (char*)sAl + lo0);
      gll16(gAl1 + k0, (char*)sAl + lo1);
      gll16(gBl0 + k0, (char*)sBl + lo0);
      gll16(gBl1 + k0, (char*)sBl + lo1);
    }
    __syncthreads();

    h8 af[4], bf[4], afl[4], bfl[4];
#pragma unroll
    for (int mi = 0; mi < 4; ++mi)
      af[mi] = *(const h8*)&sA[(wm * 64 + mi * 16 + fr) * 32 + fk];
#pragma unroll
    for (int ni = 0; ni < 4; ++ni)
      bf[ni] = *(const h8*)&sB[(wn * 64 + ni * 16 + fr) * 32 + fk];
    if constexpr (SPLIT) {
#pragma unroll
      for (int mi = 0; mi < 4; ++mi)
        afl[mi] = *(const h8*)&sAl[(wm * 64 + mi * 16 + fr) * 32 + fk];
#pragma unroll
      for (int ni = 0; ni < 4; ++ni)
        bfl[ni] = *(const h8*)&sBl[(wn * 64 + ni * 16 + fr) * 32 + fk];
    }

#pragma unroll
    for (int mi = 0; mi < 4; ++mi)
#pragma unroll
      for (int ni = 0; ni < 4; ++ni) {
        acc[mi][ni] = __builtin_amdgcn_mfma_f32_16x16x32_f16(
            af[mi], bf[ni], acc[mi][ni], 0, 0, 0);
        if constexpr (SPLIT) {
          acc[mi][ni] = __builtin_amdgcn_mfma_f32_16x16x32_f16(
              af[mi], bfl[ni], acc[mi][ni], 0, 0, 0);
          acc[mi][ni] = __builtin_amdgcn_mfma_f32_16x16x32_f16(
              afl[mi], bf[ni], acc[mi][ni], 0, 0, 0);
        }
      }
    __syncthreads();
  }

  const int drow = (lane >> 4) * 4;
  const int dcol = lane & 15;
#pragma unroll
  for (int mi = 0; mi < 4; ++mi) {
#pragma unroll
    for (int ni = 0; ni < 4; ++ni) {
      const int row = m0 + wm * 64 + mi * 16 + drow;
      const int col = n0 + wn * 64 + ni * 16 + dcol;
      f32x4 v = acc[mi][ni];
      if constexpr (EPI == EPI_S) {
#pragma unroll
        for (int r = 0; r < 4; ++r)
          of32[(size_t)(row + r) * ldc + col] = v[r];
      } else if constexpr (EPI == EPI_QK) {
#pragma unroll
        for (int r = 0; r < 4; ++r) {
          float x = v[r];
          _Float16 hh = (_Float16)x;
          size_t o = (size_t)(row + r) * ldc + col;
          oh1[o] = hh;
          oh2[o] = (_Float16)(x - (float)hh);
        }
      } else if constexpr (EPI == EPI_VT) {
        h4 hh;
#pragma unroll
        for (int r = 0; r < 4; ++r) hh[r] = (_Float16)v[r];
        *(h4*)&oh1[(size_t)col * ldt + row] = hh;
      } else {  // EPI_CTX
#pragma unroll
        for (int r = 0; r < 4; ++r) {
          size_t o = (size_t)(row + r) * ldc + col;
          of32[o] = v[r] + c1[o] + c2[o] + ((col & 1) ? 1.0f : 0.0f);
        }
      }
    }
  }
}

// ---------------------------------------------------------------------------
// 256x256 pipelined GEMM: C[M,N] = sum_p A_p[M,2048] * B_p[N,2048]^T
// 512 thr = 8 waves (2m x 4n); per-wave 128x64 out; K-tile BK=64 as 2 kk-halves.
// LDS 144KB: A[2buf][2kk][256 rows][4 slots*16B] @0 | B same @65536 | dummy @131072.
// Swizzle: phys_slot = slot ^ ((row>>1)&3); inverse applied on per-lane GLOBAL
// source (global_load_lds writes linearly). Measured 0 bank conflicts (r1).
//
// Schedule per tile t (buf = t&1), 2 SUPER-PHASES (2 barriers/tile):
//   SP0 (kk0): stage (t+1).A_k1,(t+1).B_k1 -> buf^1 | read af[0..7],bf[0..3]
//              | 32 MFMA (compiler lgkm waits) | vmcnt(8) | barrier
//   SP1 (kk1): stage (t+2).A_k0,(t+2).B_k0 -> buf   | reads +16KB | 32 MFMA
//              | vmcnt(8) | barrier
// Safety: SP1's writes hit buf.kk0, whose reads were consumed by MFMA issue
// before the SP0-end barrier. vmcnt(8) leaves exactly the 2 newest stage
// groups (8 loads/wave) in flight; everything older is resident, so after
// each barrier the next super-phase's operands are guaranteed. Past-the-end
// stages go to a dummy LDS region to keep vmcnt accounting uniform.
// ---------------------------------------------------------------------------
template<int EPI, int NPASS>
__global__ __launch_bounds__(512, 2) void gemm256(
    const _Float16* __restrict__ A0, const _Float16* __restrict__ B0,
    const _Float16* __restrict__ A1, const _Float16* __restrict__ B1,
    const _Float16* __restrict__ A2, const _Float16* __restrict__ B2,
    int lda, int ldb, int ldc,
    float* __restrict__ of32, _Float16* __restrict__ oh1,
    _Float16* __restrict__ oh2)
{
  __shared__ __align__(16) char lds[147456];
  constexpr int T = NPASS * 32;     // 32 K-tiles of 64 per 2048-deep pass

  const int tid  = threadIdx.x;
  const int lane = tid & 63;
  const int w    = tid >> 6;
  const int wm = w >> 2, wn = w & 3;
  const int fr = lane & 15, sl = lane >> 4;
  const int m0 = blockIdx.y * 256, n0 = blockIdx.x * 256;

  const int sswz  = ((sl ^ ((fr >> 1) & 3)) << 4);      // swizzled 16B slot
  const int aBase = (wm * 128 + fr) * 64 + sswz;        // byte offs in A block
  const int bBase = 65536 + (wn * 64 + fr) * 64 + sswz; // byte offs in B block
  const int rowoff = w * 16 + (lane >> 2);              // staging row
  const int sL8 = ((lane & 3) ^ ((lane >> 3) & 3)) * 8; // inv-swz global slot

  auto gstage = [&](int t, int isB, int kk) {
    const _Float16* g; int ld, r0, gk; char* dst;
    if (t >= T) {                      // dummy stage: keeps vmcnt uniform
      g = A0; ld = lda; r0 = m0; gk = 0; dst = lds + 131072;
    } else {
      const int p = t >> 5, kt = t & 31;
      g  = isB ? (p == 0 ? B0 : (p == 1 ? B1 : B2))
               : (p == 0 ? A0 : (p == 1 ? A1 : A2));
      ld = isB ? ldb : lda;
      r0 = isB ? n0 : m0;
      gk = kt * 64 + kk * 32;
      dst = lds + (isB ? 65536 : 0) + (t & 1) * 32768 + kk * 16384;
    }
#pragma unroll
    for (int i = 0; i < 2; ++i)
      gll16(g + (size_t)(r0 + i * 128 + rowoff) * ld + gk + sL8,
            dst + i * 8192 + w * 1024);
  };

  f32x4 acc[8][4];
#pragma unroll
  for (int i = 0; i < 8; ++i)
#pragma unroll
    for (int j = 0; j < 4; ++j) acc[i][j] = (f32x4){0.f, 0.f, 0.f, 0.f};

  // prologue: t0 fully + t1.kk0 (12 loads/thread); vmcnt(8) -> t0.kk0 resident.
  gstage(0, 0, 0); gstage(0, 1, 0);
  gstage(0, 0, 1); gstage(0, 1, 1);
  gstage(1, 0, 0); gstage(1, 1, 0);
  asm volatile("s_waitcnt vmcnt(8)" ::: "memory");
  __builtin_amdgcn_s_barrier();

#pragma unroll 2
  for (int t = 0; t < T; ++t) {
    const char* aB = lds + (t & 1) * 32768;

#pragma unroll
    for (int kk = 0; kk < 2; ++kk) {
      // stage first so the async loads start early
      if (kk == 0) { gstage(t + 1, 0, 1); gstage(t + 1, 1, 1); }
      else         { gstage(t + 2, 0, 0); gstage(t + 2, 1, 0); }

      const char* base = aB + kk * 16384;
      h8 af[8], bf[4];
#pragma unroll
      for (int i = 0; i < 8; ++i)
        af[i] = *(const h8*)(base + aBase + i * 1024);
#pragma unroll
      for (int i = 0; i < 4; ++i)
        bf[i] = *(const h8*)(base + bBase + i * 1024);

      __builtin_amdgcn_s_setprio(1);
#pragma unroll
      for (int mi = 0; mi < 8; ++mi)
#pragma unroll
        for (int ni = 0; ni < 4; ++ni)
          acc[mi][ni] = __builtin_amdgcn_mfma_f32_16x16x32_f16(
              af[mi], bf[ni], acc[mi][ni], 0, 0, 0);
      __builtin_amdgcn_s_setprio(0);

      asm volatile("s_waitcnt vmcnt(8)" ::: "memory");
      __builtin_amdgcn_s_barrier();
    }
  }
  asm volatile("s_waitcnt vmcnt(0)" ::: "memory");     // drain dummy stages

  // C/D frag: col = lane&15, row = (lane>>4)*4 + reg
  const int drow = sl * 4;
#pragma unroll
  for (int mi = 0; mi < 8; ++mi) {
#pragma unroll
    for (int ni = 0; ni < 4; ++ni) {
      const int row = m0 + wm * 128 + mi * 16 + drow;
      const int col = n0 + wn * 64 + ni * 16 + fr;
      f32x4 v = acc[mi][ni];
      if constexpr (EPI == EPI_S) {
#pragma unroll
        for (int r = 0; r < 4; ++r)
          of32[(size_t)(row + r) * ldc + col] = v[r];
      } else {  // EPI_QK
#pragma unroll
        for (int r = 0; r < 4; ++r) {
          float x = v[r];
          _Float16 hh = (_Float16)x;
          size_t o = (size_t)(row + r) * ldc + col;
          oh1[o] = hh;
          oh2[o] = (_Float16)(x - (float)hh);
        }
      }
    }
  }
}

// ------------- row softmax with channel bias; in-place fp32 -> fp16 --------
__global__ __launch_bounds__(256) void softmax_bias_kernel(
    float* __restrict__ S, int N)
{
  const float scale = 0.022097086912079608f;  // 1/sqrt(2048)
  const int row = blockIdx.x;
  float* rp = S + (size_t)row * N;
  const int cblk = row & ~63;  // channel block start (CW=64)
  const int tid = threadIdx.x;

  float vals[16];
  float mx = -3.0e38f;
#pragma unroll
  for (int it = 0; it < 4; ++it) {
    int base = (it * 256 + tid) * 4;
    float4 v = *(const float4*)(rp + base);
    float a[4] = {v.x, v.y, v.z, v.w};
#pragma unroll
    for (int e = 0; e < 4; ++e) {
      int col = base + e;
      float s = a[e];
      if ((col & ~63) == cblk) s += 1.0f;  // bias BEFORE scaling (reference)
      s *= scale;
      vals[it * 4 + e] = s;
      mx = fmaxf(mx, s);
    }
  }
  __shared__ float red[8];
#pragma unroll
  for (int m = 32; m; m >>= 1) mx = fmaxf(mx, __shfl_xor(mx, m, 64));
  if ((tid & 63) == 0) red[tid >> 6] = mx;
  __syncthreads();
  mx = fmaxf(fmaxf(red[0], red[1]), fmaxf(red[2], red[3]));

  float sum = 0.f;
#pragma unroll
  for (int i = 0; i < 16; ++i) {
    float e = __expf(vals[i] - mx);
    vals[i] = e;
    sum += e;
  }
#pragma unroll
  for (int m = 32; m; m >>= 1) sum += __shfl_xor(sum, m, 64);
  if ((tid & 63) == 0) red[4 + (tid >> 6)] = sum;
  __syncthreads();
  sum = red[4] + red[5] + red[6] + red[7];
  float inv = 1.0f / sum;

  _Float16* op = (_Float16*)rp;  // in-place: fp16 attn over first half of row
#pragma unroll
  for (int it = 0; it < 4; ++it) {
    int base = (it * 256 + tid) * 4;
    h4 hh;
#pragma unroll
    for (int e = 0; e < 4; ++e) hh[e] = (_Float16)(vals[it * 4 + e] * inv);
    *(h4*)(op + base) = hh;
  }
}

// ---------------------------------------------------------------------------
extern "C" void kernel_launch(void* const* d_in, const int* in_sizes, int n_in,
                              void* d_out, int out_size, void* d_ws,
                              size_t ws_size, hipStream_t stream)
{
  (void)in_sizes; (void)n_in; (void)out_size; (void)ws_size;
  const float* x   = (const float*)d_in[0];  // [4096,2048]
  const float* Wq  = (const float*)d_in[1];  // [2048,2048]
  const float* Wk  = (const float*)d_in[2];
  const float* Wv  = (const float*)d_in[3];
  const float* bch = (const float*)d_in[4];  // [4096,2048]
  const float* bt0 = (const float*)d_in[5];  // b_t[0] = first slice
  float* out = (float*)d_out;

  char* ws = (char*)d_ws;
  // phase-1 region [0, 64MiB): x split + merged W_qk split; S (64MiB fp32)
  // aliases it after the qk and v GEMMs are done with those inputs.
  const size_t O_XHI  = 0;                    // 16 MiB
  const size_t O_XLO  = O_XHI + 16777216;     // 16 MiB
  const size_t O_WQKH = O_XLO + 16777216;     // [Wq;Wk] hi, [4096][2048] fp16
  const size_t O_WQKL = O_WQKH + 16777216;    // [Wq;Wk] lo       -> 64 MiB
  const size_t O_S    = 0;                    // fp32 scores, 64 MiB (alias)
  const size_t O_WVH  = 67108864;             // 8 MiB
  const size_t O_VT   = O_WVH + 8388608;      // 16 MiB (v^T fp16)
  const size_t O_QKH  = O_VT + 16777216;      // [q|k] hi, [4096][4096] fp16
  const size_t O_QKL  = O_QKH + 33554432;     // [q|k] lo -> total 159383552 B

  _Float16* xhi  = (_Float16*)(ws + O_XHI);
  _Float16* xlo  = (_Float16*)(ws + O_XLO);
  _Float16* wqkh = (_Float16*)(ws + O_WQKH);
  _Float16* wqkl = (_Float16*)(ws + O_WQKL);
  _Float16* wvh  = (_Float16*)(ws + O_WVH);
  _Float16* vT   = (_Float16*)(ws + O_VT);
  _Float16* qkh  = (_Float16*)(ws + O_QKH);
  _Float16* qkl  = (_Float16*)(ws + O_QKL);
  float*    S    = (float*)(ws + O_S);

  // 1) split x (8.4M elems, float4-vectorized)
  split_x_kernel<<<2097152 / 256, 256, 0, stream>>>(x, xhi, xlo, 2097152);
  // 2) transpose+split weights; Wq rows 0..2047, Wk rows 2048..4095 (merged)
  dim3 tg(64, 64);
  transpose_split_w<<<tg, 256, 0, stream>>>(Wq, wqkh, wqkl, 2048, 1);
  transpose_split_w<<<tg, 256, 0, stream>>>(
      Wk, wqkh + (size_t)2048 * 2048, wqkl + (size_t)2048 * 2048, 2048, 1);
  transpose_split_w<<<tg, 256, 0, stream>>>(Wv, wvh, nullptr, 2048, 0);

  // 3) [q|k] = x @ [Wq|Wk]  -- split as 3 passes: Ahi*Bhi + Ahi*Blo + Alo*Bhi
  //    N=4096 -> grid 16x16 = 256 blocks = 1 per CU.
  gemm256<EPI_QK, 3><<<dim3(16, 16), 512, 0, stream>>>(
      xhi, wqkh, xhi, wqkl, xlo, wqkh, 2048, 2048, 4096,
      nullptr, qkh, qkl);
  // 4) vT = (x@Wv)^T  (plain fp16, 128^2 kernel: N=2048 grid fills GPU there)
  gemm_bt<EPI_VT, false><<<dim3(16, 32), 256, 0, stream>>>(
      xhi, nullptr, wvh, nullptr, 2048, 2048, 2048, 0, 4096,
      nullptr, vT, nullptr, nullptr, nullptr);

  // 5) S = q@k^T -- split 3 passes; q = qk cols 0..2047, k = qk cols 2048..4095
  gemm256<EPI_S, 3><<<dim3(16, 16), 512, 0, stream>>>(
      qkh, qkh + 2048, qkh, qkl + 2048, qkl, qkh + 2048, 4096, 4096, 4096,
      S, nullptr, nullptr);

  // 6) softmax((S + chan_bias)/sqrt(d)) -> attn fp16, in place
  softmax_bias_kernel<<<4096, 256, 0, stream>>>(S, 4096);

  // 7) out = attn@v + b_channel + b_t[0] + PE(0)  (attn lda = 8192 halves)
  gemm_bt<EPI_CTX, false><<<dim3(16, 32), 256, 0, stream>>>(
      (const _Float16*)S, nullptr, vT, nullptr, 4096, 8192, 4096, 2048, 0,
      out, nullptr, nullptr, bch, bt0);
}